// Round 13
// baseline (39.727 us; speedup 1.0000x reference)
//
#include <hip/hip_runtime.h>
#include <stdint.h>

// Problem constants
#define BB 1024
#define MM 128
#define KK 32
#define NEDGE (BB * MM * KK)   // 4194304
#define BPB 4                  // blocks per batch
#define ROWS_PER_WAVE (MM / (4 * BPB))  // 8
#define HALF (ROWS_PER_WAVE / 2)        // 4

#define TH 0x41C80000u         // f32 bits of 25.0 (low 7 bits zero)
#define INFK 0x7F800000u

typedef unsigned int uint2v __attribute__((ext_vector_type(2)));

#define DPP1 "quad_perm:[1,0,3,2] row_mask:0xf bank_mask:0xf"   // xor 1
#define DPP2 "quad_perm:[2,3,0,1] row_mask:0xf bank_mask:0xf"   // xor 2

// ---- single-key comparators (keep-min where mask bit set) ----
template<int ST>
static __device__ __forceinline__ void cexd(unsigned& k, unsigned long long msk) {
    unsigned t0, t1;
    if constexpr (ST == 1) {
        asm("s_nop 1\n\t"
            "v_min_u32_dpp %1, %0, %0 " DPP1 "\n\t"
            "v_max_u32_dpp %2, %0, %0 " DPP1 "\n\t"
            "v_cndmask_b32 %0, %2, %1, %3"
            : "+v"(k), "=&v"(t0), "=&v"(t1) : "s"(msk));
    } else {
        asm("s_nop 1\n\t"
            "v_min_u32_dpp %1, %0, %0 " DPP2 "\n\t"
            "v_max_u32_dpp %2, %0, %0 " DPP2 "\n\t"
            "v_cndmask_b32 %0, %2, %1, %3"
            : "+v"(k), "=&v"(t0), "=&v"(t1) : "s"(msk));
    }
}

template<int ST>
static __device__ __forceinline__ void cexs(unsigned& k, unsigned long long msk) {
    unsigned p = (unsigned)__builtin_amdgcn_ds_swizzle((int)k, (ST << 10) | 0x1F);
    unsigned mn = __builtin_elementwise_min(k, p);
    unsigned mx = __builtin_elementwise_max(k, p);
    asm("v_cndmask_b32 %0, %1, %2, %3" : "=v"(k) : "v"(mx), "v"(mn), "s"(msk));
}

// dual-key DPP comparator: ka/kb alternation covers the DPP hazard internally;
// s_nop 0 covers the entry (previous writer of ka is >=1 instr back + 1 nop).
#define DCEXD(KA, KB, DPPSTR, M)                                              \
  { unsigned t0_, t1_, t2_, t3_;                                              \
    asm("s_nop 0\n\t"                                                         \
        "v_min_u32_dpp %2, %0, %0 " DPPSTR "\n\t"                             \
        "v_max_u32_dpp %3, %0, %0 " DPPSTR "\n\t"                             \
        "v_min_u32_dpp %4, %1, %1 " DPPSTR "\n\t"                             \
        "v_max_u32_dpp %5, %1, %1 " DPPSTR "\n\t"                             \
        "v_cndmask_b32 %0, %3, %2, %6\n\t"                                    \
        "v_cndmask_b32 %1, %5, %4, %6"                                        \
        : "+v"(KA), "+v"(KB), "=&v"(t0_), "=&v"(t1_), "=&v"(t2_), "=&v"(t3_)  \
        : "s"(M)); }

// stride-32 compare-exchange across the 32-lane halves
static __device__ __forceinline__ void cex32f(unsigned& k, unsigned long long msk) {
#if __has_builtin(__builtin_amdgcn_permlane32_swap)
    uint2v s = __builtin_amdgcn_permlane32_swap(k, k, false, false);
    unsigned mn = __builtin_elementwise_min(s.x, s.y);
    unsigned mx = __builtin_elementwise_max(s.x, s.y);
#else
    unsigned p = (unsigned)__shfl_xor((int)k, 32, 64);
    unsigned mn = __builtin_elementwise_min(k, p);
    unsigned mx = __builtin_elementwise_max(k, p);
#endif
    asm("v_cndmask_b32 %0, %1, %2, %3" : "=v"(k) : "v"(mx), "v"(mn), "s"(msk));
}

// min over {v[l], v[l^32]}
static __device__ __forceinline__ unsigned minxor32(unsigned k) {
#if __has_builtin(__builtin_amdgcn_permlane32_swap)
    uint2v s = __builtin_amdgcn_permlane32_swap(k, k, false, false);
    return __builtin_elementwise_min(s.x, s.y);
#else
    unsigned p = (unsigned)__shfl_xor((int)k, 32, 64);
    return __builtin_elementwise_min(k, p);
#endif
}

// duplicate lanes 0..31 into lanes 32..63 (sorted ranks live in low half)
static __device__ __forceinline__ unsigned duphalf(unsigned k, unsigned long long m32) {
#if __has_builtin(__builtin_amdgcn_permlane32_swap)
    uint2v s = __builtin_amdgcn_permlane32_swap(k, k, false, false);
    unsigned partner = s.x ^ s.y ^ k;
#else
    unsigned partner = (unsigned)__shfl_xor((int)k, 32, 64);
#endif
    unsigned r;
    asm("v_cndmask_b32 %0, %1, %2, %3" : "=v"(r) : "v"(partner), "v"(k), "s"(m32));
    return r;
}

static __device__ __forceinline__ unsigned mbcnt64(unsigned long long m) {
    unsigned t = __builtin_amdgcn_mbcnt_lo((unsigned)m, 0u);
    return __builtin_amdgcn_mbcnt_hi((unsigned)(m >> 32), t);
}

// grid = BB*BPB blocks of 256 threads; each wave handles 8 rows as 4 pairs.
// Per row: 128 candidates (2/lane), key = (f32bits(max(d2,0)) & ~0x7F) | j.
// Both-fast pairs (~80%): dual LDS-compaction + interleaved dual sort-64.
// Otherwise per-row: single fast sort-64 or round-9 two-key slow network.
__global__ __launch_bounds__(256, 4) void knn_edges_kernel(const float* __restrict__ pos,
                                                           float* __restrict__ out) {
    __shared__ float px[MM], py[MM], pz[MM], sqs[MM];
    __shared__ unsigned comp[4][2][64];
    const int blk = blockIdx.x;
    const int b = blk >> 2;            // blk / BPB
    const int sub = blk & (BPB - 1);
    const int tid = threadIdx.x;

    if (tid < MM) {
        const float* p = pos + (size_t)(b * MM + tid) * 3;
        float x = p[0], y = p[1], z = p[2];
        px[tid] = x; py[tid] = y; pz[tid] = z;
        sqs[tid] = __fadd_rn(__fadd_rn(__fmul_rn(x, x), __fmul_rn(y, y)), __fmul_rn(z, z));
    }
    __syncthreads();

    const int wave = tid >> 6;
    const int lane = tid & 63;
    const int g = lane & 31;
    const bool hi = lane >= 32;
    const unsigned upper = hi ? ~0u : 0u;

    // ---- the 6 comparator masks, anchored once into SGPR pairs ----
    unsigned long long m1  = 0x5555555555555555ull;
    unsigned long long m2  = 0x3333333333333333ull;
    unsigned long long m4  = 0x0F0F0F0F0F0F0F0Full;
    unsigned long long m8  = 0x00FF00FF00FF00FFull;
    unsigned long long m16 = 0x0000FFFF0000FFFFull;
    unsigned long long m32 = 0x00000000FFFFFFFFull;
    asm("" : "+s"(m1), "+s"(m2), "+s"(m4), "+s"(m8), "+s"(m16), "+s"(m32));

    // ---- slow-path direction-fold constants (g-based, verified round 9) ----
    auto dmask = [&](int s) -> unsigned {
        unsigned zer = ((g & s) == 0) ? ~0u : 0u;
        return ~(zer ^ upper);   // XNOR
    };
    const unsigned f2    = dmask(2);
    const unsigned nf2   = ~f2;
    const unsigned f4c   = dmask(4);
    const unsigned f8c   = dmask(8);
    const unsigned f16c  = dmask(16);
    const unsigned f32c  = dmask(32);
    const unsigned t24   = f2 ^ f4c;
    const unsigned t48   = f4c ^ f8c;
    const unsigned t816  = f8c ^ f16c;
    const unsigned t1632 = f16c ^ f32c;
    const unsigned nf32  = ~f32c;

    // ---- fast-path fold constants (full-lane based, for the 64-sort) ----
    auto ff = [&](int s) -> unsigned { return (lane & s) ? ~0u : 0u; };
    const unsigned u2    = ff(2);
    const unsigned s24   = u2 ^ ff(4);
    const unsigned s48   = ff(4) ^ ff(8);
    const unsigned s816  = ff(8) ^ ff(16);
    const unsigned s1632 = ff(16) ^ ff(32);
    const unsigned u32   = ff(32);

    // single-row fast path (round-12 verified): compact + s_nop'd sort-64
    auto fast_single = [&](int slot, unsigned k0r, unsigned k1r,
                           unsigned long long mask0, unsigned long long mask1,
                           unsigned c0, unsigned nsurv) -> unsigned {
        if (k0r < TH) comp[wave][slot][mbcnt64(mask0)] = k0r;
        if (k1r < TH) comp[wave][slot][c0 + mbcnt64(mask1)] = k1r;
        asm volatile("s_waitcnt lgkmcnt(0)" ::: "memory");
        unsigned k = comp[wave][slot][lane];
        k = ((unsigned)lane < nsurv) ? k : INFK;
        k ^= u2;
        cexd<1>(k, m1);
        k ^= s24;
        cexd<2>(k, m2); cexd<1>(k, m1);
        k ^= s48;
        cexs<4>(k, m4); cexd<2>(k, m2); cexd<1>(k, m1);
        k ^= s816;
        cexs<8>(k, m8); cexs<4>(k, m4); cexd<2>(k, m2); cexd<1>(k, m1);
        k ^= s1632;
        cexs<16>(k, m16); cexs<8>(k, m8); cexs<4>(k, m4);
        cexd<2>(k, m2); cexd<1>(k, m1);
        k ^= u32;
        cex32f(k, m32); cexs<16>(k, m16); cexs<8>(k, m8); cexs<4>(k, m4);
        cexd<2>(k, m2); cexd<1>(k, m1);
        return duphalf(k, m32);
    };

    // slow path (round-9 verified two-key network)
    auto slow_sort = [&](unsigned k0r, unsigned k1r) -> unsigned {
        unsigned K0 = k0r ^ f2;
        unsigned K1 = k1r ^ nf2;
#define SS2(ST, MSK) cexs<ST>(K0, MSK); cexs<ST>(K1, MSK);
        SS2(1, m1)
        K0 ^= t24; K1 ^= t24;
        SS2(2, m2) SS2(1, m1)
        K0 ^= t48; K1 ^= t48;
        SS2(4, m4) SS2(2, m2) SS2(1, m1)
        K0 ^= t816; K1 ^= t816;
        SS2(8, m8) SS2(4, m4) SS2(2, m2) SS2(1, m1)
        K0 ^= t1632; K1 ^= t1632;
        SS2(16, m16) SS2(8, m8) SS2(4, m4) SS2(2, m2) SS2(1, m1)
#undef SS2
        unsigned Ca = (__builtin_elementwise_min(K0 ^ f32c, K1 ^ nf32)) ^ upper;
        cexs<16>(Ca, m16); cexs<8>(Ca, m8); cexs<4>(Ca, m4);
        cexs<2>(Ca, m2);  cexs<1>(Ca, m1);
        unsigned Ma = minxor32(Ca ^ upper);
        cexs<16>(Ma, m16); cexs<8>(Ma, m8); cexs<4>(Ma, m4);
        cexs<2>(Ma, m2);  cexs<1>(Ma, m1);
        return Ma;
    };

    // per-lane candidate coordinates, hoisted across the row loop
    const int j0 = lane, j1 = lane + 64;
    const float xa = px[j0], ya = py[j0], za = pz[j0], qa = sqs[j0];
    const float xb = px[j1], yb = py[j1], zb = pz[j1], qb = sqs[j1];

    const int row0 = sub * (MM / BPB) + wave * ROWS_PER_WAVE;
    const float fbase = (float)(b * MM);   // exact in fp32

    // output streams (3 stores/lane/row); row-b of a pair at +HALF offsets
    float* const vecbase = out + 3 * (size_t)NEDGE;
    const long e0 = (long)(b * MM + row0) * KK + g;
    float* pA = hi ? out + (size_t)NEDGE + e0 : out + e0;
    float* pB = vecbase + e0 * 3 + (hi ? 2 : 0);
    float* pC = hi ? out + 2 * (size_t)NEDGE + e0 : vecbase + e0 * 3 + 1;
    const int sC = hi ? KK : 3 * KK;
    const int oC = sC * HALF;

    for (int ii = 0; ii < HALF; ++ii) {
        const int ia = row0 + ii;
        const int ib = ia + HALF;

        const float xia = px[ia], yia = py[ia], zia = pz[ia], qia = sqs[ia];
        const float xib = px[ib], yib = py[ib], zib = pz[ib], qib = sqs[ib];

        // ---- raw candidate keys for both rows ----
        float dot;
        dot = fmaf(xia, xa, fmaf(yia, ya, zia * za));
        unsigned k0a = (__float_as_uint(fmaxf(fmaf(-2.0f, dot, qia + qa), 0.0f)) & 0xFFFFFF80u) | (unsigned)j0;
        dot = fmaf(xia, xb, fmaf(yia, yb, zia * zb));
        unsigned k1a = (__float_as_uint(fmaxf(fmaf(-2.0f, dot, qia + qb), 0.0f)) & 0xFFFFFF80u) | (unsigned)j1;
        dot = fmaf(xib, xa, fmaf(yib, ya, zib * za));
        unsigned k0b = (__float_as_uint(fmaxf(fmaf(-2.0f, dot, qib + qa), 0.0f)) & 0xFFFFFF80u) | (unsigned)j0;
        dot = fmaf(xib, xb, fmaf(yib, yb, zib * zb));
        unsigned k1b = (__float_as_uint(fmaxf(fmaf(-2.0f, dot, qib + qb), 0.0f)) & 0xFFFFFF80u) | (unsigned)j1;

        // ---- survivor census (wave-uniform) ----
        unsigned long long mask0a = __ballot(k0a < TH), mask1a = __ballot(k1a < TH);
        unsigned long long mask0b = __ballot(k0b < TH), mask1b = __ballot(k1b < TH);
        unsigned c0a = (unsigned)__popcll(mask0a);
        unsigned na  = c0a + (unsigned)__popcll(mask1a);
        unsigned c0b = (unsigned)__popcll(mask0b);
        unsigned nb  = c0b + (unsigned)__popcll(mask1b);

        unsigned Ma, Mb;
        if (na <= 64u && nb <= 64u) {
            // ===== DUAL FAST PATH: compact both rows, interleaved sort-64 ====
            if (k0a < TH) comp[wave][0][mbcnt64(mask0a)] = k0a;
            if (k1a < TH) comp[wave][0][c0a + mbcnt64(mask1a)] = k1a;
            if (k0b < TH) comp[wave][1][mbcnt64(mask0b)] = k0b;
            if (k1b < TH) comp[wave][1][c0b + mbcnt64(mask1b)] = k1b;
            asm volatile("s_waitcnt lgkmcnt(0)" ::: "memory");
            unsigned ka = comp[wave][0][lane];
            unsigned kb = comp[wave][1][lane];
            ka = ((unsigned)lane < na) ? ka : INFK;
            kb = ((unsigned)lane < nb) ? kb : INFK;

            ka ^= u2; kb ^= u2;
            DCEXD(ka, kb, DPP1, m1)
            ka ^= s24; kb ^= s24;
            DCEXD(ka, kb, DPP2, m2)
            DCEXD(ka, kb, DPP1, m1)
            ka ^= s48; kb ^= s48;
            cexs<4>(ka, m4); cexs<4>(kb, m4);
            DCEXD(ka, kb, DPP2, m2)
            DCEXD(ka, kb, DPP1, m1)
            ka ^= s816; kb ^= s816;
            cexs<8>(ka, m8); cexs<8>(kb, m8);
            cexs<4>(ka, m4); cexs<4>(kb, m4);
            DCEXD(ka, kb, DPP2, m2)
            DCEXD(ka, kb, DPP1, m1)
            ka ^= s1632; kb ^= s1632;
            cexs<16>(ka, m16); cexs<16>(kb, m16);
            cexs<8>(ka, m8);   cexs<8>(kb, m8);
            cexs<4>(ka, m4);   cexs<4>(kb, m4);
            DCEXD(ka, kb, DPP2, m2)
            DCEXD(ka, kb, DPP1, m1)
            ka ^= u32; kb ^= u32;
            cex32f(ka, m32); cex32f(kb, m32);
            cexs<16>(ka, m16); cexs<16>(kb, m16);
            cexs<8>(ka, m8);   cexs<8>(kb, m8);
            cexs<4>(ka, m4);   cexs<4>(kb, m4);
            DCEXD(ka, kb, DPP2, m2)
            DCEXD(ka, kb, DPP1, m1)

            Ma = duphalf(ka, m32);
            Mb = duphalf(kb, m32);
        } else {
            Ma = (na <= 64u) ? fast_single(0, k0a, k1a, mask0a, mask1a, c0a, na)
                             : slow_sort(k0a, k1a);
            Mb = (nb <= 64u) ? fast_single(1, k0b, k1b, mask0b, mask1b, c0b, nb)
                             : slow_sort(k0b, k1b);
        }

        // ---- epilogue row a ----
        {
            const bool taken = Ma < TH;
            const int j = (int)(Ma & 127u);
            const int sel = taken ? j : ia;
            float dxv = __fsub_rn(px[sel], xia);
            float dyv = __fsub_rn(py[sel], yia);
            float dzv = __fsub_rn(pz[sel], zia);
            float w = sqrtf(fmaf(dzv, dzv, fmaf(dyv, dyv, dxv * dxv)));
            const float fsrc = fbase + (float)sel;
            const float fnode = fbase + (float)ia;
            pA[0] = hi ? fnode : fsrc;
            pB[0] = hi ? dzv : dxv;
            pC[0] = hi ? w : dyv;
        }
        // ---- epilogue row b ----
        {
            const bool taken = Mb < TH;
            const int j = (int)(Mb & 127u);
            const int sel = taken ? j : ib;
            float dxv = __fsub_rn(px[sel], xib);
            float dyv = __fsub_rn(py[sel], yib);
            float dzv = __fsub_rn(pz[sel], zib);
            float w = sqrtf(fmaf(dzv, dzv, fmaf(dyv, dyv, dxv * dxv)));
            const float fsrc = fbase + (float)sel;
            const float fnode = fbase + (float)ib;
            pA[HALF * KK] = hi ? fnode : fsrc;
            pB[HALF * 3 * KK] = hi ? dzv : dxv;
            pC[oC] = hi ? w : dyv;
        }
        pA += KK; pB += 3 * KK; pC += sC;
    }
}

extern "C" void kernel_launch(void* const* d_in, const int* in_sizes, int n_in,
                              void* d_out, int out_size, void* d_ws, size_t ws_size,
                              hipStream_t stream) {
    const float* pos = (const float*)d_in[0];
    float* out = (float*)d_out;
    hipLaunchKernelGGL(knn_edges_kernel, dim3(BB * BPB), dim3(256), 0, stream, pos, out);
}

// Round 14
// 39.176 us; speedup vs baseline: 1.0141x; 1.0141x over previous
//
#include <hip/hip_runtime.h>
#include <stdint.h>

// Problem constants
#define BB 1024
#define MM 128
#define KK 32
#define NEDGE (BB * MM * KK)   // 4194304
#define BPB 4                  // blocks per batch
#define ROWS_PER_WAVE (MM / (4 * BPB))  // 8
#define HALF (ROWS_PER_WAVE / 2)        // 4

#define TH 0x41C80000u         // f32 bits of 25.0 (low 7 bits zero)
#define INFK 0x7F800000u

typedef unsigned int uint2v __attribute__((ext_vector_type(2)));

#define DPP1 "quad_perm:[1,0,3,2] row_mask:0xf bank_mask:0xf"   // xor 1
#define DPP2 "quad_perm:[2,3,0,1] row_mask:0xf bank_mask:0xf"   // xor 2

// ---- single-key comparators (keep-min where mask bit set) ----
template<int ST>
static __device__ __forceinline__ void cexd(unsigned& k, unsigned long long msk) {
    unsigned t0, t1;
    if constexpr (ST == 1) {
        asm("s_nop 1\n\t"
            "v_min_u32_dpp %1, %0, %0 " DPP1 "\n\t"
            "v_max_u32_dpp %2, %0, %0 " DPP1 "\n\t"
            "v_cndmask_b32 %0, %2, %1, %3"
            : "+v"(k), "=&v"(t0), "=&v"(t1) : "s"(msk));
    } else {
        asm("s_nop 1\n\t"
            "v_min_u32_dpp %1, %0, %0 " DPP2 "\n\t"
            "v_max_u32_dpp %2, %0, %0 " DPP2 "\n\t"
            "v_cndmask_b32 %0, %2, %1, %3"
            : "+v"(k), "=&v"(t0), "=&v"(t1) : "s"(msk));
    }
}

template<int ST>
static __device__ __forceinline__ void cexs(unsigned& k, unsigned long long msk) {
    unsigned p = (unsigned)__builtin_amdgcn_ds_swizzle((int)k, (ST << 10) | 0x1F);
    unsigned mn = __builtin_elementwise_min(k, p);
    unsigned mx = __builtin_elementwise_max(k, p);
    asm("v_cndmask_b32 %0, %1, %2, %3" : "=v"(k) : "v"(mx), "v"(mn), "s"(msk));
}

// dual-key DPP comparator (ka/kb alternation covers the DPP hazard)
#define DCEXD(KA, KB, DPPSTR, M)                                              \
  { unsigned t0_, t1_, t2_, t3_;                                              \
    asm("s_nop 0\n\t"                                                         \
        "v_min_u32_dpp %2, %0, %0 " DPPSTR "\n\t"                             \
        "v_max_u32_dpp %3, %0, %0 " DPPSTR "\n\t"                             \
        "v_min_u32_dpp %4, %1, %1 " DPPSTR "\n\t"                             \
        "v_max_u32_dpp %5, %1, %1 " DPPSTR "\n\t"                             \
        "v_cndmask_b32 %0, %3, %2, %6\n\t"                                    \
        "v_cndmask_b32 %1, %5, %4, %6"                                        \
        : "+v"(KA), "+v"(KB), "=&v"(t0_), "=&v"(t1_), "=&v"(t2_), "=&v"(t3_)  \
        : "s"(M)); }

// stride-32 compare-exchange across the 32-lane halves
static __device__ __forceinline__ void cex32f(unsigned& k, unsigned long long msk) {
#if __has_builtin(__builtin_amdgcn_permlane32_swap)
    uint2v s = __builtin_amdgcn_permlane32_swap(k, k, false, false);
    unsigned mn = __builtin_elementwise_min(s.x, s.y);
    unsigned mx = __builtin_elementwise_max(s.x, s.y);
#else
    unsigned p = (unsigned)__shfl_xor((int)k, 32, 64);
    unsigned mn = __builtin_elementwise_min(k, p);
    unsigned mx = __builtin_elementwise_max(k, p);
#endif
    asm("v_cndmask_b32 %0, %1, %2, %3" : "=v"(k) : "v"(mx), "v"(mn), "s"(msk));
}

// min over {v[l], v[l^32]}
static __device__ __forceinline__ unsigned minxor32(unsigned k) {
#if __has_builtin(__builtin_amdgcn_permlane32_swap)
    uint2v s = __builtin_amdgcn_permlane32_swap(k, k, false, false);
    return __builtin_elementwise_min(s.x, s.y);
#else
    unsigned p = (unsigned)__shfl_xor((int)k, 32, 64);
    return __builtin_elementwise_min(k, p);
#endif
}

// duplicate lanes 0..31 into lanes 32..63
static __device__ __forceinline__ unsigned duphalf(unsigned k, unsigned long long m32) {
#if __has_builtin(__builtin_amdgcn_permlane32_swap)
    uint2v s = __builtin_amdgcn_permlane32_swap(k, k, false, false);
    unsigned partner = s.x ^ s.y ^ k;
#else
    unsigned partner = (unsigned)__shfl_xor((int)k, 32, 64);
#endif
    unsigned r;
    asm("v_cndmask_b32 %0, %1, %2, %3" : "=v"(r) : "v"(partner), "v"(k), "s"(m32));
    return r;
}

static __device__ __forceinline__ unsigned mbcnt64(unsigned long long m) {
    unsigned t = __builtin_amdgcn_mbcnt_lo((unsigned)m, 0u);
    return __builtin_amdgcn_mbcnt_hi((unsigned)(m >> 32), t);
}

// grid = BB*BPB blocks of 256 threads; each wave handles 8 rows as 4 pairs.
// key = (f32bits(max(d2,0)) & ~0x7F) | j.
// PAIR32 (both rows <=32 survivors): both rows share ONE 15-stage sort-32
//   chain (row A in lanes 0-31, row B in lanes 32-63; strides<=16 never
//   cross halves), single per-pair epilogue.
// Else dual-fast (<=64,<=64), else per-row fast/slow (round-13 verified).
__global__ __launch_bounds__(256, 4) void knn_edges_kernel(const float* __restrict__ pos,
                                                           float* __restrict__ out) {
    __shared__ float px[MM], py[MM], pz[MM], sqs[MM];
    __shared__ unsigned comp[4][2][64];
    const int blk = blockIdx.x;
    const int b = blk >> 2;            // blk / BPB
    const int sub = blk & (BPB - 1);
    const int tid = threadIdx.x;

    if (tid < MM) {
        const float* p = pos + (size_t)(b * MM + tid) * 3;
        float x = p[0], y = p[1], z = p[2];
        px[tid] = x; py[tid] = y; pz[tid] = z;
        sqs[tid] = __fadd_rn(__fadd_rn(__fmul_rn(x, x), __fmul_rn(y, y)), __fmul_rn(z, z));
    }
    __syncthreads();

    const int wave = tid >> 6;
    const int lane = tid & 63;
    const int g = lane & 31;
    const bool hi = lane >= 32;
    const unsigned upper = hi ? ~0u : 0u;

    // ---- the 6 comparator masks, anchored once into SGPR pairs ----
    unsigned long long m1  = 0x5555555555555555ull;
    unsigned long long m2  = 0x3333333333333333ull;
    unsigned long long m4  = 0x0F0F0F0F0F0F0F0Full;
    unsigned long long m8  = 0x00FF00FF00FF00FFull;
    unsigned long long m16 = 0x0000FFFF0000FFFFull;
    unsigned long long m32 = 0x00000000FFFFFFFFull;
    asm("" : "+s"(m1), "+s"(m2), "+s"(m4), "+s"(m8), "+s"(m16), "+s"(m32));

    // ---- slow-path direction-fold constants (g-based, verified round 9) ----
    auto dmask = [&](int s) -> unsigned {
        unsigned zer = ((g & s) == 0) ? ~0u : 0u;
        return ~(zer ^ upper);   // XNOR
    };
    const unsigned f2    = dmask(2);
    const unsigned nf2   = ~f2;
    const unsigned f4c   = dmask(4);
    const unsigned f8c   = dmask(8);
    const unsigned f16c  = dmask(16);
    const unsigned f32c  = dmask(32);
    const unsigned t24   = f2 ^ f4c;
    const unsigned t48   = f4c ^ f8c;
    const unsigned t816  = f8c ^ f16c;
    const unsigned t1632 = f16c ^ f32c;
    const unsigned nf32  = ~f32c;

    // ---- fast-path fold constants ----
    auto ff = [&](int s) -> unsigned { return (lane & s) ? ~0u : 0u; };
    const unsigned u2    = ff(2);
    const unsigned s24   = u2 ^ ff(4);
    const unsigned s48   = ff(4) ^ ff(8);
    const unsigned s816  = ff(8) ^ ff(16);
    const unsigned f16v  = ff(16);
    const unsigned s1632 = f16v ^ ff(32);
    const unsigned u32   = ff(32);

    // single-row fast path (round-12 verified): compact + sort-64
    auto fast_single = [&](int slot, unsigned k0r, unsigned k1r,
                           unsigned long long mask0, unsigned long long mask1,
                           unsigned c0, unsigned nsurv) -> unsigned {
        if (k0r < TH) comp[wave][slot][mbcnt64(mask0)] = k0r;
        if (k1r < TH) comp[wave][slot][c0 + mbcnt64(mask1)] = k1r;
        asm volatile("s_waitcnt lgkmcnt(0)" ::: "memory");
        unsigned k = comp[wave][slot][lane];
        k = ((unsigned)lane < nsurv) ? k : INFK;
        k ^= u2;
        cexd<1>(k, m1);
        k ^= s24;
        cexd<2>(k, m2); cexd<1>(k, m1);
        k ^= s48;
        cexs<4>(k, m4); cexd<2>(k, m2); cexd<1>(k, m1);
        k ^= s816;
        cexs<8>(k, m8); cexs<4>(k, m4); cexd<2>(k, m2); cexd<1>(k, m1);
        k ^= s1632;
        cexs<16>(k, m16); cexs<8>(k, m8); cexs<4>(k, m4);
        cexd<2>(k, m2); cexd<1>(k, m1);
        k ^= u32;
        cex32f(k, m32); cexs<16>(k, m16); cexs<8>(k, m8); cexs<4>(k, m4);
        cexd<2>(k, m2); cexd<1>(k, m1);
        return duphalf(k, m32);
    };

    // slow path (round-9 verified two-key network)
    auto slow_sort = [&](unsigned k0r, unsigned k1r) -> unsigned {
        unsigned K0 = k0r ^ f2;
        unsigned K1 = k1r ^ nf2;
#define SS2(ST, MSK) cexs<ST>(K0, MSK); cexs<ST>(K1, MSK);
        SS2(1, m1)
        K0 ^= t24; K1 ^= t24;
        SS2(2, m2) SS2(1, m1)
        K0 ^= t48; K1 ^= t48;
        SS2(4, m4) SS2(2, m2) SS2(1, m1)
        K0 ^= t816; K1 ^= t816;
        SS2(8, m8) SS2(4, m4) SS2(2, m2) SS2(1, m1)
        K0 ^= t1632; K1 ^= t1632;
        SS2(16, m16) SS2(8, m8) SS2(4, m4) SS2(2, m2) SS2(1, m1)
#undef SS2
        unsigned Ca = (__builtin_elementwise_min(K0 ^ f32c, K1 ^ nf32)) ^ upper;
        cexs<16>(Ca, m16); cexs<8>(Ca, m8); cexs<4>(Ca, m4);
        cexs<2>(Ca, m2);  cexs<1>(Ca, m1);
        unsigned Ma = minxor32(Ca ^ upper);
        cexs<16>(Ma, m16); cexs<8>(Ma, m8); cexs<4>(Ma, m4);
        cexs<2>(Ma, m2);  cexs<1>(Ma, m1);
        return Ma;
    };

    // per-lane candidate coordinates, hoisted across the row loop
    const int j0 = lane, j1 = lane + 64;
    const float xa = px[j0], ya = py[j0], za = pz[j0], qa = sqs[j0];
    const float xb = px[j1], yb = py[j1], zb = pz[j1], qb = sqs[j1];

    const int row0 = sub * (MM / BPB) + wave * ROWS_PER_WAVE;
    const float fbase = (float)(b * MM);   // exact in fp32

    // output streams for the non-pair paths (3 stores/lane/row)
    float* const vecbase = out + 3 * (size_t)NEDGE;
    const long e0 = (long)(b * MM + row0) * KK + g;
    float* pA = hi ? out + (size_t)NEDGE + e0 : out + e0;
    float* pB = vecbase + e0 * 3 + (hi ? 2 : 0);
    float* pC = hi ? out + 2 * (size_t)NEDGE + e0 : vecbase + e0 * 3 + 1;
    const int sC = hi ? KK : 3 * KK;
    const int oC = sC * HALF;

    for (int ii = 0; ii < HALF; ++ii) {
        const int ia = row0 + ii;
        const int ib = ia + HALF;

        const float xia = px[ia], yia = py[ia], zia = pz[ia], qia = sqs[ia];
        const float xib = px[ib], yib = py[ib], zib = pz[ib], qib = sqs[ib];

        // ---- raw candidate keys for both rows ----
        float dot;
        dot = fmaf(xia, xa, fmaf(yia, ya, zia * za));
        unsigned k0a = (__float_as_uint(fmaxf(fmaf(-2.0f, dot, qia + qa), 0.0f)) & 0xFFFFFF80u) | (unsigned)j0;
        dot = fmaf(xia, xb, fmaf(yia, yb, zia * zb));
        unsigned k1a = (__float_as_uint(fmaxf(fmaf(-2.0f, dot, qia + qb), 0.0f)) & 0xFFFFFF80u) | (unsigned)j1;
        dot = fmaf(xib, xa, fmaf(yib, ya, zib * za));
        unsigned k0b = (__float_as_uint(fmaxf(fmaf(-2.0f, dot, qib + qa), 0.0f)) & 0xFFFFFF80u) | (unsigned)j0;
        dot = fmaf(xib, xb, fmaf(yib, yb, zib * zb));
        unsigned k1b = (__float_as_uint(fmaxf(fmaf(-2.0f, dot, qib + qb), 0.0f)) & 0xFFFFFF80u) | (unsigned)j1;

        // ---- survivor census (wave-uniform) ----
        unsigned long long mask0a = __ballot(k0a < TH), mask1a = __ballot(k1a < TH);
        unsigned long long mask0b = __ballot(k0b < TH), mask1b = __ballot(k1b < TH);
        unsigned c0a = (unsigned)__popcll(mask0a);
        unsigned na  = c0a + (unsigned)__popcll(mask1a);
        unsigned c0b = (unsigned)__popcll(mask0b);
        unsigned nb  = c0b + (unsigned)__popcll(mask1b);

        if (na <= 32u && nb <= 32u) {
            // ===== PAIR32: one shared sort-32 chain for both rows =====
            if (k0a < TH) comp[wave][0][mbcnt64(mask0a)] = k0a;
            if (k1a < TH) comp[wave][0][c0a + mbcnt64(mask1a)] = k1a;
            if (k0b < TH) comp[wave][0][32u + mbcnt64(mask0b)] = k0b;
            if (k1b < TH) comp[wave][0][32u + c0b + mbcnt64(mask1b)] = k1b;
            asm volatile("s_waitcnt lgkmcnt(0)" ::: "memory");
            unsigned k = comp[wave][0][lane];
            k = ((unsigned)g < (hi ? nb : na)) ? k : INFK;

            // sort-32 in g-space (15 stages), ascending final, both halves
            k ^= u2;
            cexd<1>(k, m1);
            k ^= s24;
            cexd<2>(k, m2); cexd<1>(k, m1);
            k ^= s48;
            cexs<4>(k, m4); cexd<2>(k, m2); cexd<1>(k, m1);
            k ^= s816;
            cexs<8>(k, m8); cexs<4>(k, m4); cexd<2>(k, m2); cexd<1>(k, m1);
            k ^= f16v;
            cexs<16>(k, m16); cexs<8>(k, m8); cexs<4>(k, m4);
            cexd<2>(k, m2); cexd<1>(k, m1);

            // ---- per-pair epilogue: lo half = row a, hi half = row b ----
            const bool taken = k < TH;
            const int j = (int)(k & 127u);
            const int rowi = hi ? ib : ia;
            const float xr = hi ? xib : xia;
            const float yr = hi ? yib : yia;
            const float zr = hi ? zib : zia;
            const int sel = taken ? j : rowi;
            float dxv = __fsub_rn(px[sel], xr);
            float dyv = __fsub_rn(py[sel], yr);
            float dzv = __fsub_rn(pz[sel], zr);
            float w = sqrtf(fmaf(dzv, dzv, fmaf(dyv, dyv, dxv * dxv)));
            const float fsrc = fbase + (float)sel;
            const float fnd  = fbase + (float)rowi;
            const long eH = e0 + (long)ii * KK + (hi ? (long)HALF * KK : 0);
            out[eH] = fsrc;
            out[(size_t)NEDGE + eH] = fnd;
            out[2 * (size_t)NEDGE + eH] = w;
            float* v = vecbase + eH * 3;
            v[0] = dxv; v[1] = dyv; v[2] = dzv;
        } else {
            unsigned Ma, Mb;
            if (na <= 64u && nb <= 64u) {
                // ===== DUAL FAST: compact both rows, interleaved sort-64 ====
                if (k0a < TH) comp[wave][0][mbcnt64(mask0a)] = k0a;
                if (k1a < TH) comp[wave][0][c0a + mbcnt64(mask1a)] = k1a;
                if (k0b < TH) comp[wave][1][mbcnt64(mask0b)] = k0b;
                if (k1b < TH) comp[wave][1][c0b + mbcnt64(mask1b)] = k1b;
                asm volatile("s_waitcnt lgkmcnt(0)" ::: "memory");
                unsigned ka = comp[wave][0][lane];
                unsigned kb = comp[wave][1][lane];
                ka = ((unsigned)lane < na) ? ka : INFK;
                kb = ((unsigned)lane < nb) ? kb : INFK;

                ka ^= u2; kb ^= u2;
                DCEXD(ka, kb, DPP1, m1)
                ka ^= s24; kb ^= s24;
                DCEXD(ka, kb, DPP2, m2)
                DCEXD(ka, kb, DPP1, m1)
                ka ^= s48; kb ^= s48;
                cexs<4>(ka, m4); cexs<4>(kb, m4);
                DCEXD(ka, kb, DPP2, m2)
                DCEXD(ka, kb, DPP1, m1)
                ka ^= s816; kb ^= s816;
                cexs<8>(ka, m8); cexs<8>(kb, m8);
                cexs<4>(ka, m4); cexs<4>(kb, m4);
                DCEXD(ka, kb, DPP2, m2)
                DCEXD(ka, kb, DPP1, m1)
                ka ^= s1632; kb ^= s1632;
                cexs<16>(ka, m16); cexs<16>(kb, m16);
                cexs<8>(ka, m8);   cexs<8>(kb, m8);
                cexs<4>(ka, m4);   cexs<4>(kb, m4);
                DCEXD(ka, kb, DPP2, m2)
                DCEXD(ka, kb, DPP1, m1)
                ka ^= u32; kb ^= u32;
                cex32f(ka, m32); cex32f(kb, m32);
                cexs<16>(ka, m16); cexs<16>(kb, m16);
                cexs<8>(ka, m8);   cexs<8>(kb, m8);
                cexs<4>(ka, m4);   cexs<4>(kb, m4);
                DCEXD(ka, kb, DPP2, m2)
                DCEXD(ka, kb, DPP1, m1)

                Ma = duphalf(ka, m32);
                Mb = duphalf(kb, m32);
            } else {
                Ma = (na <= 64u) ? fast_single(0, k0a, k1a, mask0a, mask1a, c0a, na)
                                 : slow_sort(k0a, k1a);
                Mb = (nb <= 64u) ? fast_single(1, k0b, k1b, mask0b, mask1b, c0b, nb)
                                 : slow_sort(k0b, k1b);
            }

            // ---- dual epilogue (round-13 verified) ----
            {
                const bool taken = Ma < TH;
                const int j = (int)(Ma & 127u);
                const int sel = taken ? j : ia;
                float dxv = __fsub_rn(px[sel], xia);
                float dyv = __fsub_rn(py[sel], yia);
                float dzv = __fsub_rn(pz[sel], zia);
                float w = sqrtf(fmaf(dzv, dzv, fmaf(dyv, dyv, dxv * dxv)));
                const float fsrc = fbase + (float)sel;
                const float fnode = fbase + (float)ia;
                pA[0] = hi ? fnode : fsrc;
                pB[0] = hi ? dzv : dxv;
                pC[0] = hi ? w : dyv;
            }
            {
                const bool taken = Mb < TH;
                const int j = (int)(Mb & 127u);
                const int sel = taken ? j : ib;
                float dxv = __fsub_rn(px[sel], xib);
                float dyv = __fsub_rn(py[sel], yib);
                float dzv = __fsub_rn(pz[sel], zib);
                float w = sqrtf(fmaf(dzv, dzv, fmaf(dyv, dyv, dxv * dxv)));
                const float fsrc = fbase + (float)sel;
                const float fnode = fbase + (float)ib;
                pA[HALF * KK] = hi ? fnode : fsrc;
                pB[HALF * 3 * KK] = hi ? dzv : dxv;
                pC[oC] = hi ? w : dyv;
            }
        }
        pA += KK; pB += 3 * KK; pC += sC;
    }
}

extern "C" void kernel_launch(void* const* d_in, const int* in_sizes, int n_in,
                              void* d_out, int out_size, void* d_ws, size_t ws_size,
                              hipStream_t stream) {
    const float* pos = (const float*)d_in[0];
    float* out = (float*)d_out;
    hipLaunchKernelGGL(knn_edges_kernel, dim3(BB * BPB), dim3(256), 0, stream, pos, out);
}